// Round 1
// baseline (505.176 us; speedup 1.0000x reference)
//
#include <hip/hip_runtime.h>
#include <hip/hip_bf16.h>
#include <stdint.h>

#define NTOK 8192
#define XSTRIDE 259
#define LOG2E 1.4426950408889634f
#define KSPLIT 8
#define SPLEN (NTOK / KSPLIT)   /* 1024 */
#define ITERS (SPLEN / 64)      /* 16 */

typedef __bf16 bf16x8 __attribute__((ext_vector_type(8)));
typedef float f32x4 __attribute__((ext_vector_type(4)));
typedef uint32_t u32x4 __attribute__((ext_vector_type(4)));
typedef unsigned short u16;

union BF8 { u16 u[8]; bf16x8 v; };

__device__ __forceinline__ u16 f2bf(float f) {
  uint32_t u = __float_as_uint(f);
  u += 0x7FFFu + ((u >> 16) & 1u);
  return (u16)(u >> 16);
}
__device__ __forceinline__ float bf2f(u16 h) {
  return __uint_as_float(((uint32_t)h) << 16);
}
__device__ __forceinline__ float exp2_hw(float x) {
  float r; asm("v_exp_f32 %0, %1" : "=v"(r) : "v"(x)); return r;
}
template<int CTRL>
__device__ __forceinline__ float dpp_rot(float x) {
  int i = __float_as_int(x);
  int y = __builtin_amdgcn_update_dpp(i, i, CTRL, 0xF, 0xF, false);
  return __int_as_float(y);
}
// reductions across the 16-lane DPP row (lanes sharing q4, i.e. one C-layout col group)
__device__ __forceinline__ float rowmax16(float x) {
  x = fmaxf(x, dpp_rot<0x121>(x));  // row_ror:1
  x = fmaxf(x, dpp_rot<0x122>(x));  // row_ror:2
  x = fmaxf(x, dpp_rot<0x124>(x));  // row_ror:4
  x = fmaxf(x, dpp_rot<0x128>(x));  // row_ror:8
  return x;
}
__device__ __forceinline__ float rowsum16(float x) {
  x += dpp_rot<0x121>(x);
  x += dpp_rot<0x122>(x);
  x += dpp_rot<0x124>(x);
  x += dpp_rot<0x128>(x);
  return x;
}
__device__ __forceinline__ f32x4 mfma16(bf16x8 a, bf16x8 b, f32x4 c) {
  return __builtin_amdgcn_mfma_f32_16x16x32_bf16(a, b, c, 0, 0, 0);
}

// ---------------------------------------------------------------------------
// Kernel 0: P / |P|^2 precompute.  pq[row] = (px, py, pz, 0.5*|P|^2)
// ---------------------------------------------------------------------------
__global__ void pq_kernel(const float* __restrict__ X, float* __restrict__ pq) {
  int r = blockIdx.x * 256 + threadIdx.x;
  const float* xp = X + (size_t)r * XSTRIDE + 256;
  float x = xp[0], y = xp[1], z = xp[2];
  f32x4 o = { x, y, z, 0.5f * (x * x + y * y + z * z) };
  ((f32x4*)pq)[r] = o;
}

// ---------------------------------------------------------------------------
// Kernel 1: QKV projection (bf16 MFMA).  grid (64 rowblocks, 12 col-chunks).
// chunk ch: which = ch>>2 (0=Q,1=K,2=V), cols (ch&3)*64 .. +64
// Q,K written row-major [8192][256] bf16; V written transposed Vt[256][8192].
// ---------------------------------------------------------------------------
__global__ __launch_bounds__(256) void qkv_kernel(
    const float* __restrict__ X,
    const float* __restrict__ WQ, const float* __restrict__ bQ,
    const float* __restrict__ WK, const float* __restrict__ bK,
    const float* __restrict__ WV, const float* __restrict__ bV,
    u16* __restrict__ Qb, u16* __restrict__ Kb, u16* __restrict__ Vt) {
  __shared__ u16 wt[64 * 264];   // W^T chunk [64 out][256 in], pad 8 -> 16B rows
  const int tid = threadIdx.x;
  const int lane = tid & 63;
  const int wave = tid >> 6;
  const int l15 = lane & 15;
  const int q4 = lane >> 4;
  const int rb = blockIdx.x;
  const int ch = blockIdx.y;
  const int which = ch >> 2;
  const int c0 = (ch & 3) * 64;
  const float* W = (which == 0) ? WQ : ((which == 1) ? WK : WV);
  const float* bias = (which == 0) ? bQ : ((which == 1) ? bK : bV);

  {
    const int j = tid & 63;
    const int k0 = tid >> 6;
#pragma unroll
    for (int i = 0; i < 64; ++i) {
      int k = k0 + i * 4;
      wt[j * 264 + k] = f2bf(W[k * 256 + c0 + j]);
    }
  }
  // X fragments (A-operand): wave covers 32 rows
  bf16x8 xa[2][8];
#pragma unroll
  for (int mt = 0; mt < 2; ++mt) {
    const int row = rb * 128 + wave * 32 + mt * 16 + l15;
#pragma unroll
    for (int kc = 0; kc < 8; ++kc) {
      const float* xp = X + (size_t)row * XSTRIDE + kc * 32 + q4 * 8;
      BF8 u;
#pragma unroll
      for (int jj = 0; jj < 8; ++jj) u.u[jj] = f2bf(xp[jj]);
      xa[mt][kc] = u.v;
    }
  }
  __syncthreads();

  f32x4 acc[2][4];
#pragma unroll
  for (int mt = 0; mt < 2; ++mt)
#pragma unroll
    for (int nt = 0; nt < 4; ++nt) acc[mt][nt] = (f32x4){0.f, 0.f, 0.f, 0.f};

#pragma unroll
  for (int kc = 0; kc < 8; ++kc) {
#pragma unroll
    for (int nt = 0; nt < 4; ++nt) {
      bf16x8 wf = *(const bf16x8*)(wt + (nt * 16 + l15) * 264 + kc * 32 + q4 * 8);
#pragma unroll
      for (int mt = 0; mt < 2; ++mt)
        acc[mt][nt] = mfma16(xa[mt][kc], wf, acc[mt][nt]);
    }
  }
  float bc[4];
#pragma unroll
  for (int nt = 0; nt < 4; ++nt) bc[nt] = bias[c0 + nt * 16 + l15];

#pragma unroll
  for (int mt = 0; mt < 2; ++mt)
#pragma unroll
    for (int nt = 0; nt < 4; ++nt)
#pragma unroll
      for (int r = 0; r < 4; ++r) {
        float v = acc[mt][nt][r] + bc[nt];
        int grow = rb * 128 + wave * 32 + mt * 16 + q4 * 4 + r;
        int gc = c0 + nt * 16 + l15;
        if (which == 2)      Vt[(size_t)gc * NTOK + grow] = f2bf(v);
        else if (which == 1) Kb[(size_t)grow * 256 + gc] = f2bf(v);
        else                 Qb[(size_t)grow * 256 + gc] = f2bf(v);
      }
}

// ---------------------------------------------------------------------------
// Kernel 2: flash attention with spatial decay, split-K over keys.
// grid (64 rowblocks, 8 splits); 256 threads = 4 waves, M=32 rows/wave.
// Writes per-split partial O (bf16) and (m,l) per row.
// ---------------------------------------------------------------------------
__global__ __launch_bounds__(256, 2) void attn_kernel(
    const u16* __restrict__ Qb, const u16* __restrict__ Kb,
    const u16* __restrict__ Vt, const float* __restrict__ pq,
    u16* __restrict__ Op, float* __restrict__ ml) {
  __shared__ u16 kbuf[64 * 264];   // K tile [64 keys][256], pad 8; P tiles aliased here
  __shared__ u16 vbuf[256 * 72];   // V^T tile [256 feat][64 keys], pad 8
  __shared__ float pqs[128][4];    // block rows' (px,py,pz,hq)

  const int tid = threadIdx.x;
  const int lane = tid & 63;
  const int wave = tid >> 6;
  const int l15 = lane & 15;
  const int q4 = lane >> 4;
  const int rb = blockIdx.x;
  const int sp = blockIdx.y;
  const int q0 = rb * 128;

  if (tid < 128) ((f32x4*)pqs)[tid] = ((const f32x4*)pq)[q0 + tid];

  int zf; asm volatile("s_mov_b32 %0, 0" : "=s"(zf));  // opaque 0: keeps Q loads in-loop

  f32x4 O[2][16];
#pragma unroll
  for (int mt = 0; mt < 2; ++mt)
#pragma unroll
    for (int ft = 0; ft < 16; ++ft) O[mt][ft] = (f32x4){0.f, 0.f, 0.f, 0.f};
  float mrow[8], lrow[8];
#pragma unroll
  for (int i = 0; i < 8; ++i) { mrow[i] = -1e30f; lrow[i] = 0.f; }

  u16* swave = kbuf + wave * (32 * 72);  // per-wave P-tile region (aliased on kbuf)
  const int wrow = wave * 32;

#pragma unroll 1
  for (int it = 0; it < ITERS; ++it) {
    const int key0 = sp * SPLEN + it * 64;
    // ---- stage K tile (64x256) ----
#pragma unroll
    for (int i = 0; i < 8; ++i) {
      int C = i * 256 + tid;
      int r = C >> 5, cb = C & 31;
      *(u32x4*)(kbuf + r * 264 + cb * 8) =
          *(const u32x4*)(Kb + (size_t)(key0 + r) * 256 + cb * 8);
    }
    // ---- stage V^T tile (256x64) ----
#pragma unroll
    for (int i = 0; i < 8; ++i) {
      int C = i * 256 + tid;
      int f = C >> 3, cb = C & 7;
      *(u32x4*)(vbuf + f * 72 + cb * 8) =
          *(const u32x4*)(Vt + (size_t)f * NTOK + key0 + cb * 8);
    }
    __syncthreads();

    // ---- S = Q K^T (raw dot; scale folded into decay exponent) ----
    f32x4 S[2][4];
#pragma unroll
    for (int mt = 0; mt < 2; ++mt)
#pragma unroll
      for (int nt = 0; nt < 4; ++nt) S[mt][nt] = (f32x4){0.f, 0.f, 0.f, 0.f};

    const u16* qit = Qb + (size_t)(zf * it);
#pragma unroll
    for (int kc = 0; kc < 8; ++kc) {
      bf16x8 qa[2];
#pragma unroll
      for (int mt = 0; mt < 2; ++mt)
        qa[mt] = *(const bf16x8*)(qit + (size_t)(q0 + wrow + mt * 16 + l15) * 256 +
                                  kc * 32 + q4 * 8);
#pragma unroll
      for (int nt = 0; nt < 4; ++nt) {
        bf16x8 kf = *(const bf16x8*)(kbuf + (nt * 16 + l15) * 264 + kc * 32 + q4 * 8);
#pragma unroll
        for (int mt = 0; mt < 2; ++mt)
          S[mt][nt] = mfma16(qa[mt], kf, S[mt][nt]);
      }
    }

    // ---- decay + online softmax (x and p kept in S regs) ----
    f32x4 pk[4];
#pragma unroll
    for (int nt = 0; nt < 4; ++nt)
      pk[nt] = ((const f32x4*)pq)[key0 + nt * 16 + l15];

    float newm[8], rsum[8];
    bool anynew = false;
#pragma unroll
    for (int mt = 0; mt < 2; ++mt) {
#pragma unroll
      for (int r = 0; r < 4; ++r) {
        const int ri = mt * 4 + r;
        f32x4 pr = *(const f32x4*)pqs[wrow + mt * 16 + q4 * 4 + r];
        float xm = -1e30f;
#pragma unroll
        for (int nt = 0; nt < 4; ++nt) {
          float d2h = pr[3] + pk[nt][3] -
                      (pr[0] * pk[nt][0] + pr[1] * pk[nt][1] + pr[2] * pk[nt][2]);
          d2h = fmaxf(d2h, 0.f);
          // decay/16 = 2^(-d2h*log2e - 4)
          float dec = exp2_hw(fmaf(d2h, -LOG2E, -4.0f));
          float x = S[mt][nt][r] * dec;
          S[mt][nt][r] = x;
          xm = fmaxf(xm, x);
        }
        xm = rowmax16(xm);
        float nm = fmaxf(mrow[ri], xm);
        newm[ri] = nm;
        anynew |= (nm > mrow[ri]);
        float rs = 0.f;
#pragma unroll
        for (int nt = 0; nt < 4; ++nt) {
          float p = exp2_hw((S[mt][nt][r] - nm) * LOG2E);
          S[mt][nt][r] = p;
          rs += p;
        }
        rsum[ri] = rowsum16(rs);
      }
    }
    if (__any((int)anynew)) {
      float alpha[8];
#pragma unroll
      for (int i = 0; i < 8; ++i) alpha[i] = exp2_hw((mrow[i] - newm[i]) * LOG2E);
#pragma unroll
      for (int mt = 0; mt < 2; ++mt)
#pragma unroll
        for (int ft = 0; ft < 16; ++ft)
#pragma unroll
          for (int r = 0; r < 4; ++r) O[mt][ft][r] *= alpha[mt * 4 + r];
#pragma unroll
      for (int i = 0; i < 8; ++i) lrow[i] = lrow[i] * alpha[i] + rsum[i];
    } else {
#pragma unroll
      for (int i = 0; i < 8; ++i) lrow[i] += rsum[i];
    }
#pragma unroll
    for (int i = 0; i < 8; ++i) mrow[i] = newm[i];

    __syncthreads();  // all waves done reading kbuf before P overwrites it

    // ---- P tile (bf16) into per-wave LDS region ----
#pragma unroll
    for (int mt = 0; mt < 2; ++mt)
#pragma unroll
      for (int nt = 0; nt < 4; ++nt)
#pragma unroll
        for (int r = 0; r < 4; ++r)
          swave[(mt * 16 + q4 * 4 + r) * 72 + nt * 16 + l15] = f2bf(S[mt][nt][r]);

    // ---- O += P V ----
#pragma unroll
    for (int kc2 = 0; kc2 < 2; ++kc2) {
      bf16x8 pa[2];
#pragma unroll
      for (int mt = 0; mt < 2; ++mt)
        pa[mt] = *(const bf16x8*)(swave + (mt * 16 + l15) * 72 + kc2 * 32 + q4 * 8);
#pragma unroll
      for (int ft = 0; ft < 16; ++ft) {
        bf16x8 vf = *(const bf16x8*)(vbuf + (ft * 16 + l15) * 72 + kc2 * 32 + q4 * 8);
#pragma unroll
        for (int mt = 0; mt < 2; ++mt)
          O[mt][ft] = mfma16(pa[mt], vf, O[mt][ft]);
      }
    }
    __syncthreads();  // P/V tiles free for next iteration's staging
  }

  // ---- write partial O, (m, l) ----
#pragma unroll
  for (int mt = 0; mt < 2; ++mt)
#pragma unroll
    for (int ft = 0; ft < 16; ++ft)
#pragma unroll
      for (int r = 0; r < 4; ++r) {
        int row = q0 + wrow + mt * 16 + q4 * 4 + r;
        Op[((size_t)sp * NTOK + row) * 256 + ft * 16 + l15] = f2bf(O[mt][ft][r]);
      }
  if (l15 == 0) {
#pragma unroll
    for (int mt = 0; mt < 2; ++mt)
#pragma unroll
      for (int r = 0; r < 4; ++r) {
        int row = q0 + wrow + mt * 16 + q4 * 4 + r;
        ((float2*)ml)[sp * NTOK + row] = make_float2(mrow[mt * 4 + r], lrow[mt * 4 + r]);
      }
  }
}

// ---------------------------------------------------------------------------
// Kernel 3: combine splits, normalize with (1 + sum e), add residual Xf.
// ---------------------------------------------------------------------------
__global__ __launch_bounds__(256) void combine_kernel(
    const float* __restrict__ X, const u16* __restrict__ Op,
    const float* __restrict__ ml, float* __restrict__ out) {
  const int row = blockIdx.x;
  const int f = threadIdx.x;
  float mm[KSPLIT], ll[KSPLIT];
  float M = -1e30f;
#pragma unroll
  for (int s = 0; s < KSPLIT; ++s) {
    float2 v = ((const float2*)ml)[s * NTOK + row];
    mm[s] = v.x; ll[s] = v.y;
    M = fmaxf(M, v.x);
  }
  float den = 1.f, num = 0.f;
#pragma unroll
  for (int s = 0; s < KSPLIT; ++s) {
    float w = exp2_hw((mm[s] - M) * LOG2E);
    den += ll[s] * w;
    num += bf2f(Op[((size_t)s * NTOK + row) * 256 + f]) * w;
  }
  out[(size_t)row * 256 + f] = num / den + X[(size_t)row * XSTRIDE + f];
}

// ---------------------------------------------------------------------------
extern "C" void kernel_launch(void* const* d_in, const int* in_sizes, int n_in,
                              void* d_out, int out_size, void* d_ws, size_t ws_size,
                              hipStream_t stream) {
  (void)in_sizes; (void)n_in; (void)out_size; (void)ws_size;
  const float* X  = (const float*)d_in[0];
  const float* WQ = (const float*)d_in[1];
  const float* bQ = (const float*)d_in[2];
  const float* WK = (const float*)d_in[3];
  const float* bK = (const float*)d_in[4];
  const float* WV = (const float*)d_in[5];
  const float* bV = (const float*)d_in[6];
  float* out = (float*)d_out;
  char* ws = (char*)d_ws;

  // workspace layout (bytes): Qb 4M | Kb 4M | Vt 4M | pq 128K | Op 32M | ml 512K
  u16*   Qb = (u16*)(ws);
  u16*   Kb = (u16*)(ws + (size_t)4 * 1024 * 1024);
  u16*   Vt = (u16*)(ws + (size_t)8 * 1024 * 1024);
  float* pq = (float*)(ws + (size_t)12 * 1024 * 1024);
  u16*   Op = (u16*)(ws + (size_t)12 * 1024 * 1024 + 131072);
  float* ml = (float*)(ws + (size_t)12 * 1024 * 1024 + 131072 +
                       (size_t)KSPLIT * NTOK * 256 * 2);

  pq_kernel<<<dim3(NTOK / 256), dim3(256), 0, stream>>>(X, pq);
  qkv_kernel<<<dim3(64, 12), dim3(256), 0, stream>>>(X, WQ, bQ, WK, bK, WV, bV,
                                                     Qb, Kb, Vt);
  attn_kernel<<<dim3(64, KSPLIT), dim3(256), 0, stream>>>(Qb, Kb, Vt, pq, Op, ml);
  combine_kernel<<<dim3(NTOK), dim3(256), 0, stream>>>(X, Op, ml, out);
}